// Round 1
// baseline (345.750 us; speedup 1.0000x reference)
//
#include <hip/hip_runtime.h>
#include <math.h>

#define B_    32
#define C_    384
#define RHO_  25
#define WP_   256
#define HC_   64
#define WC_   64
#define PIX_  4096   // 64*64
#define D_    768
#define HID_  40

// ---------------- zero the bin matrix ----------------
__global__ void zero_kernel(float* __restrict__ p, int n4) {
    int i = blockIdx.x * blockDim.x + threadIdx.x;
    if (i < n4) ((float4*)p)[i] = make_float4(0.f, 0.f, 0.f, 0.f);
}

// ---------------- scatter bilinear weights into per-(b,rho) pixel bins ----------------
// bins[b][rho][y*64+x] += weight/256  (mean over width folded in)
__global__ void bin_kernel(const float* __restrict__ grid, float* __restrict__ bins) {
    int pt = blockIdx.x * 256 + threadIdx.x;          // 0 .. 204799
    int b   = pt / (RHO_ * WP_);
    int rem = pt % (RHO_ * WP_);
    int rho = rem / WP_;
    float gx = grid[(size_t)pt * 2 + 0];
    float gy = grid[(size_t)pt * 2 + 1];
    float ix = (gx + 1.f) * 32.f - 0.5f;              // W*0.5 = 32
    float iy = (gy + 1.f) * 32.f - 0.5f;              // H*0.5 = 32
    float x0f = floorf(ix), y0f = floorf(iy);
    float fx = ix - x0f, fy = iy - y0f;
    int x0 = (int)x0f, y0 = (int)y0f;
    float* base = bins + (size_t)(b * RHO_ + rho) * PIX_;
    const float s = 1.f / 256.f;
    bool xv0 = (x0 >= 0) & (x0 < WC_);
    bool xv1 = (x0 + 1 >= 0) & (x0 + 1 < WC_);
    bool yv0 = (y0 >= 0) & (y0 < HC_);
    bool yv1 = (y0 + 1 >= 0) & (y0 + 1 < HC_);
    if (xv0 && yv0) atomicAdd(base + y0 * WC_ + x0,           (1.f - fx) * (1.f - fy) * s);
    if (xv1 && yv0) atomicAdd(base + y0 * WC_ + x0 + 1,       fx * (1.f - fy) * s);
    if (xv0 && yv1) atomicAdd(base + (y0 + 1) * WC_ + x0,     (1.f - fx) * fy * s);
    if (xv1 && yv1) atomicAdd(base + (y0 + 1) * WC_ + x0 + 1, fx * fy * s);
}

// ---------------- polar half: mean over width, one wave per row ----------------
// fe[rho][b][c] for c in 0..383
__global__ void polar_mean_kernel(const float* __restrict__ polar, float* __restrict__ fe) {
    int wave = threadIdx.x >> 6, lane = threadIdx.x & 63;
    int r = blockIdx.x * 4 + wave;                    // 0 .. 307199, row = (b,c,rho)
    const float4* src = (const float4*)(polar + (size_t)r * 256);
    float4 v = src[lane];                             // 64 lanes * 16B = full row
    float s = v.x + v.y + v.z + v.w;
    #pragma unroll
    for (int m = 32; m >= 1; m >>= 1) s += __shfl_xor(s, m, 64);
    if (lane == 0) {
        int rho = r % RHO_;
        int c   = (r / RHO_) % C_;
        int b   = r / (RHO_ * C_);
        fe[((size_t)(rho * B_ + b)) * D_ + c] = s * (1.f / 256.f);
    }
}

// ---------------- cart half as dense GEMM: fe_cart[b,c,rho] = sum_p bins[b,rho,p]*cart[b,c,p] ----------------
// block = (b, 32-channel tile); p tiled by 128 through LDS
__global__ __launch_bounds__(256) void cart_gemm_kernel(const float* __restrict__ cart,
                                                        const float* __restrict__ bins,
                                                        float* __restrict__ fe) {
    __shared__ float smem[7424];               // ldsW[25][128]=3200  | ldsX[32][132]=4224 (padded)
    float* ldsW = smem;
    float* ldsX = smem + 3200;
    int b  = blockIdx.x / 12;
    int c0 = (blockIdx.x % 12) * 32;
    int tid = threadIdx.x;
    int c = tid & 31, q = tid >> 5;            // thread owns channel c, p-stripe q
    float acc[25];
    #pragma unroll
    for (int r = 0; r < 25; r++) acc[r] = 0.f;
    const float* binb  = bins + (size_t)b * RHO_ * PIX_;
    const float* cartb = cart + ((size_t)b * C_ + c0) * PIX_;

    for (int t = 0; t < 32; ++t) {
        int p0 = t * 128;
        // W tile: 25 x 128 floats (800 float4), coalesced
        for (int idx = tid; idx < 800; idx += 256) {
            int rho = idx >> 5, c4 = idx & 31;
            float4 v = *(const float4*)(binb + (size_t)rho * PIX_ + p0 + c4 * 4);
            *(float4*)(ldsW + rho * 128 + c4 * 4) = v;
        }
        // X tile: 32 x 128 floats (1024 float4), coalesced; padded stride 132 (=33 float4, 16B aligned)
        for (int idx = tid; idx < 1024; idx += 256) {
            int row = idx >> 5, c4 = idx & 31;
            float4 v = *(const float4*)(cartb + (size_t)row * PIX_ + p0 + c4 * 4);
            *(float4*)(ldsX + row * 132 + c4 * 4) = v;
        }
        __syncthreads();
        #pragma unroll
        for (int k = 0; k < 4; k++) {
            int m = q + 8 * k;                 // this thread's float4-quad within the 128-p tile
            float4 x4 = *(const float4*)(ldsX + c * 132 + 4 * m);
            #pragma unroll
            for (int r = 0; r < 25; r++) {
                float4 w4 = *(const float4*)(ldsW + r * 128 + 4 * m);   // 2 addrs/wave -> broadcast
                acc[r] += x4.x * w4.x + x4.y * w4.y + x4.z * w4.z + x4.w * w4.w;
            }
        }
        __syncthreads();
    }
    // reduce the 8 q-stripes per channel via LDS (once per block)
    #pragma unroll
    for (int r = 0; r < 25; r++) smem[tid * 25 + r] = acc[r];
    __syncthreads();
    for (int oi = tid; oi < 800; oi += 256) {
        int cc = oi / 25, rho = oi % 25;
        float s = 0.f;
        #pragma unroll
        for (int qq = 0; qq < 8; qq++) s += smem[((qq << 5) + cc) * 25 + rho];
        fe[((size_t)(rho * B_ + b)) * D_ + 384 + c0 + cc] = s;
    }
}

// ---------------- parallel part of MLP heads: G[i][b][j] = fe[i][b][:] @ W1 + b1 ----------------
__global__ void mlp_pre_kernel(const float* __restrict__ fe,
                               const float* __restrict__ W1_0, const float* __restrict__ b1_0,
                               const float* __restrict__ W1s,  const float* __restrict__ b1s,
                               float* __restrict__ G) {
    int oi = blockIdx.x * 256 + threadIdx.x;   // 0 .. 31999
    if (oi >= 25 * 32 * HID_) return;
    int j = oi % HID_;
    int b = (oi / HID_) % B_;
    int i = oi / (B_ * HID_);
    const float* W; float bias;
    if (i == 0) { W = W1_0;                      bias = b1_0[j]; }
    else        { W = W1s + (size_t)(i - 1) * 769 * HID_; bias = b1s[(i - 1) * HID_ + j]; }
    const float* f = fe + (size_t)(i * B_ + b) * D_;
    float acc = bias;
    #pragma unroll 8
    for (int cidx = 0; cidx < D_; cidx++) acc += f[cidx] * W[cidx * HID_ + j];
    G[oi] = acc;
}

// ---------------- sequential chain: rank-1 update + gelu + 40-dot per head ----------------
__device__ __forceinline__ float gelu_exact(float x) {
    return 0.5f * x * (1.f + erff(x * 0.70710678118654752f));
}

__global__ __launch_bounds__(1024) void mlp_seq_kernel(const float* __restrict__ G,
        const float* __restrict__ W1s, const float* __restrict__ W2_0, const float* __restrict__ b2_0,
        const float* __restrict__ W2s, const float* __restrict__ b2s, float* __restrict__ out) {
    __shared__ float o_lds[B_];
    int t = threadIdx.x;
    int b = t >> 5, j2 = t & 31;               // 32 lanes per batch row
    float op = 0.f;
    for (int i = 0; i < 25; i++) {
        float wl1 = 0.f, wl2 = 0.f, w2a, w2b = 0.f, bias2;
        if (i == 0) {
            w2a = W2_0[j2]; if (j2 < 8) w2b = W2_0[j2 + 32];
            bias2 = b2_0[0];
        } else {
            size_t base1 = ((size_t)(i - 1) * 769 + 768) * HID_;
            wl1 = W1s[base1 + j2]; if (j2 < 8) wl2 = W1s[base1 + j2 + 32];
            w2a = W2s[(i - 1) * HID_ + j2]; if (j2 < 8) w2b = W2s[(i - 1) * HID_ + j2 + 32];
            bias2 = b2s[i - 1];
        }
        const float* g = G + (size_t)(i * B_ + b) * HID_;
        float x1 = g[j2] + op * wl1;
        float x2 = (j2 < 8) ? (g[j2 + 32] + op * wl2) : 0.f;
        float partial = gelu_exact(x1) * w2a + gelu_exact(x2) * w2b;
        #pragma unroll
        for (int m = 16; m >= 1; m >>= 1) partial += __shfl_xor(partial, m, 64);
        if (j2 == 0) {
            float o = partial + bias2;
            o_lds[b] = o;                                   // unclipped feeds the chain
            out[b * 25 + i] = fminf(fmaxf(o, 0.f), 3.14159265358979323846f);
        }
        __syncthreads();
        op = o_lds[b];
        __syncthreads();
    }
}

extern "C" void kernel_launch(void* const* d_in, const int* in_sizes, int n_in,
                              void* d_out, int out_size, void* d_ws, size_t ws_size,
                              hipStream_t stream) {
    const float* polar = (const float*)d_in[0];
    const float* cart  = (const float*)d_in[1];
    const float* grid  = (const float*)d_in[2];
    const float* W1_0  = (const float*)d_in[3];
    const float* b1_0  = (const float*)d_in[4];
    const float* W2_0  = (const float*)d_in[5];
    const float* b2_0  = (const float*)d_in[6];
    const float* W1s   = (const float*)d_in[7];
    const float* b1s   = (const float*)d_in[8];
    const float* W2s   = (const float*)d_in[9];
    const float* b2s   = (const float*)d_in[10];
    float* out = (float*)d_out;

    // workspace layout (floats): bins[32*25*4096] | fe[25*32*768] | G[25*32*40]  (~15.7 MB)
    float* bins = (float*)d_ws;
    float* fe   = bins + (size_t)B_ * RHO_ * PIX_;
    float* G    = fe + (size_t)RHO_ * B_ * D_;

    int nbin4 = (B_ * RHO_ * PIX_) / 4;                    // 819200 float4
    zero_kernel<<<(nbin4 + 255) / 256, 256, 0, stream>>>(bins, nbin4);
    bin_kernel<<<(B_ * RHO_ * WP_) / 256, 256, 0, stream>>>(grid, bins);
    polar_mean_kernel<<<(B_ * C_ * RHO_) / 4, 256, 0, stream>>>(polar, fe);
    cart_gemm_kernel<<<B_ * 12, 256, 0, stream>>>(cart, bins, fe);
    mlp_pre_kernel<<<(25 * B_ * HID_ + 255) / 256, 256, 0, stream>>>(fe, W1_0, b1_0, W1s, b1s, G);
    mlp_seq_kernel<<<1, 1024, 0, stream>>>(G, W1s, W2_0, b2_0, W2s, b2s, out);
}